// Round 1
// baseline (370.212 us; speedup 1.0000x reference)
//
#include <hip/hip_runtime.h>
#include <hip/hip_fp16.h>

#define B_ 4
#define S_ 2048
#define H_ 1024
#define M_ (B_ * S_)  // 8192 flattened rows of x / q / k / v

typedef _Float16 f16;
typedef _Float16 f16x8 __attribute__((ext_vector_type(8)));
typedef _Float16 f16x4 __attribute__((ext_vector_type(4)));
typedef float f32x4 __attribute__((ext_vector_type(4)));

typedef __attribute__((address_space(3))) unsigned int* lds_u32p;
typedef const __attribute__((address_space(1))) unsigned int* gbl_u32p;

// async global->LDS, 16B per lane; LDS dest is wave-uniform base + lane*16
__device__ __forceinline__ void stage16(const f16* g, f16* l) {
  __builtin_amdgcn_global_load_lds((gbl_u32p)g, (lds_u32p)l, 16, 0, 0);
}

// ---------------------------------------------------------------------------
// x (fp32) -> hi (fp16) + lo (fp16 residual).  hi+lo reproduces x to ~2^-22.
__global__ __launch_bounds__(256) void split_fp32(const float* __restrict__ x,
                                                  f16* __restrict__ hi,
                                                  f16* __restrict__ lo,
                                                  int n4) {
  int i = blockIdx.x * 256 + threadIdx.x;
  if (i >= n4) return;
  f32x4 v = ((const f32x4*)x)[i];
  f16x4 h, l;
#pragma unroll
  for (int c = 0; c < 4; c++) {
    f16 hv = (f16)v[c];
    h[c] = hv;
    l[c] = (f16)(v[c] - (float)hv);
  }
  ((f16x4*)hi)[i] = h;
  ((f16x4*)lo)[i] = l;
}

// ---------------------------------------------------------------------------
// Fused QKV projection: qkv[sel][m][n] = quantize( x[m][:] . W_sel[n][:] + b_sel[n] )
// A = x (hi/lo fp16 split), B = W (hi/lo), NT GEMM, 128x128 tile, BK=32.
// 3-term product: x_hi*W_hi + x_hi*W_lo + x_lo*W_hi  (lo*lo negligible).
__global__ __launch_bounds__(256, 2)
void qkv_gemm(const f16* __restrict__ xh, const f16* __restrict__ xl,
              const f16* __restrict__ Wh, const f16* __restrict__ Wl,
              const float* __restrict__ bq, const float* __restrict__ bk,
              const float* __restrict__ bv, f16* __restrict__ qkv) {
  __shared__ __align__(16) f16 As[2 * 128 * 32];  // [hi | lo]
  __shared__ __align__(16) f16 Bs[2 * 128 * 32];
  const int t = threadIdx.x;
  const int wave = t >> 6, lane = t & 63;
  const int quad = lane >> 4, l16 = lane & 15;
  const int wm = (wave & 1) * 64, wn = (wave >> 1) * 64;
  const int sel = blockIdx.y >> 3;             // 0=q 1=k 2=v
  const int ntile = (blockIdx.y & 7) * 128;
  const int mtile = blockIdx.x * 128;

  const f16* Abh = xh + (long)mtile * H_;
  const f16* Abl = xl + (long)mtile * H_;
  const f16* Bbh = Wh + (long)sel * H_ * H_ + (long)ntile * H_;
  const f16* Bbl = Wl + (long)sel * H_ * H_ + (long)ntile * H_;

  const int r0 = t >> 2;        // staging row 0..63
  const int c8 = (t & 3) * 8;   // staging col (halfs)

  f32x4 acc[4][4] = {};

  for (int k0 = 0; k0 < H_; k0 += 32) {
    __syncthreads();
    stage16(Abh + (long)r0 * H_ + k0 + c8,        As + t * 8);
    stage16(Abh + (long)(r0 + 64) * H_ + k0 + c8, As + 2048 + t * 8);
    stage16(Abl + (long)r0 * H_ + k0 + c8,        As + 4096 + t * 8);
    stage16(Abl + (long)(r0 + 64) * H_ + k0 + c8, As + 6144 + t * 8);
    stage16(Bbh + (long)r0 * H_ + k0 + c8,        Bs + t * 8);
    stage16(Bbh + (long)(r0 + 64) * H_ + k0 + c8, Bs + 2048 + t * 8);
    stage16(Bbl + (long)r0 * H_ + k0 + c8,        Bs + 4096 + t * 8);
    stage16(Bbl + (long)(r0 + 64) * H_ + k0 + c8, Bs + 6144 + t * 8);
    __syncthreads();
    f16x8 ah[4], al[4], bh[4], bl[4];
#pragma unroll
    for (int i = 0; i < 4; i++) {
      ah[i] = *(const f16x8*)&As[(wm + i * 16 + l16) * 32 + quad * 8];
      al[i] = *(const f16x8*)&As[4096 + (wm + i * 16 + l16) * 32 + quad * 8];
      bh[i] = *(const f16x8*)&Bs[(wn + i * 16 + l16) * 32 + quad * 8];
      bl[i] = *(const f16x8*)&Bs[4096 + (wn + i * 16 + l16) * 32 + quad * 8];
    }
#pragma unroll
    for (int i = 0; i < 4; i++)
#pragma unroll
      for (int j = 0; j < 4; j++) {
        // small terms first for accumulation accuracy
        acc[i][j] = __builtin_amdgcn_mfma_f32_16x16x32_f16(al[i], bh[j], acc[i][j], 0, 0, 0);
        acc[i][j] = __builtin_amdgcn_mfma_f32_16x16x32_f16(ah[i], bl[j], acc[i][j], 0, 0, 0);
        acc[i][j] = __builtin_amdgcn_mfma_f32_16x16x32_f16(ah[i], bh[j], acc[i][j], 0, 0, 0);
      }
  }

  const float* bias = sel == 0 ? bq : (sel == 1 ? bk : bv);
  f16* out = qkv + (long)sel * M_ * H_;
#pragma unroll
  for (int j = 0; j < 4; j++) {
    int n = ntile + wn + j * 16 + l16;
    float bb = bias[n];
#pragma unroll
    for (int i = 0; i < 4; i++) {
      int m = mtile + wm + i * 16 + quad * 4;
#pragma unroll
      for (int r = 0; r < 4; r++)
        out[(long)(m + r) * H_ + n] = (f16)(acc[i][j][r] + bb);
    }
  }
}

// ---------------------------------------------------------------------------
// Generic batched NT fp16 GEMM: C[z][m][n] = alpha * sum_k A[z][m][k]*B[z][n][k]
// OUT_F16=1: store quantized fp16; OUT_F16=0: store fp32.
template <int OUT_F16>
__global__ __launch_bounds__(256, 2)
void gemm_nt(const f16* __restrict__ A, const f16* __restrict__ Bm,
             void* __restrict__ C, int lda, int ldb, int ldc, int K,
             long sA, long sB, long sC, float alpha) {
  __shared__ __align__(16) f16 As[128 * 32];
  __shared__ __align__(16) f16 Bs[128 * 32];
  const int t = threadIdx.x;
  const int wave = t >> 6, lane = t & 63;
  const int quad = lane >> 4, l16 = lane & 15;
  const int wm = (wave & 1) * 64, wn = (wave >> 1) * 64;
  const f16* Ab = A + blockIdx.z * sA + (long)blockIdx.x * 128 * lda;
  const f16* Bb = Bm + blockIdx.z * sB + (long)blockIdx.y * 128 * ldb;
  const int r0 = t >> 2, c8 = (t & 3) * 8;
  f32x4 acc[4][4] = {};
  for (int k0 = 0; k0 < K; k0 += 32) {
    __syncthreads();
    stage16(Ab + (long)r0 * lda + k0 + c8,        As + t * 8);
    stage16(Ab + (long)(r0 + 64) * lda + k0 + c8, As + 2048 + t * 8);
    stage16(Bb + (long)r0 * ldb + k0 + c8,        Bs + t * 8);
    stage16(Bb + (long)(r0 + 64) * ldb + k0 + c8, Bs + 2048 + t * 8);
    __syncthreads();
    f16x8 af[4], bf[4];
#pragma unroll
    for (int i = 0; i < 4; i++) {
      af[i] = *(const f16x8*)&As[(wm + i * 16 + l16) * 32 + quad * 8];
      bf[i] = *(const f16x8*)&Bs[(wn + i * 16 + l16) * 32 + quad * 8];
    }
#pragma unroll
    for (int i = 0; i < 4; i++)
#pragma unroll
      for (int j = 0; j < 4; j++)
        acc[i][j] = __builtin_amdgcn_mfma_f32_16x16x32_f16(af[i], bf[j], acc[i][j], 0, 0, 0);
  }
  const long mb = (long)blockIdx.x * 128 + wm;
  const long nb = (long)blockIdx.y * 128 + wn;
#pragma unroll
  for (int i = 0; i < 4; i++)
#pragma unroll
    for (int j = 0; j < 4; j++) {
      long m = mb + i * 16 + quad * 4;
      long n = nb + j * 16 + l16;
#pragma unroll
      for (int r = 0; r < 4; r++) {
        float v = acc[i][j][r] * alpha;
        if (OUT_F16)
          ((f16*)C)[blockIdx.z * sC + (m + r) * ldc + n] = (f16)v;
        else
          ((float*)C)[blockIdx.z * sC + (m + r) * ldc + n] = v;
      }
    }
}

// ---------------------------------------------------------------------------
// v [b][t][h] -> vT [b][h][t]  (64x64 LDS tiles, fp16)
__global__ __launch_bounds__(256) void transpose_v(const f16* __restrict__ v,
                                                   f16* __restrict__ vT) {
  __shared__ __align__(16) f16 tile[64][72];
  const int b = blockIdx.z;
  const int t0 = blockIdx.x * 64;
  const int h0 = blockIdx.y * 64;
  const int t = threadIdx.x;
  const int tx = t & 7, ty = t >> 3;
#pragma unroll
  for (int it = 0; it < 2; it++) {
    int r = ty + it * 32;  // t-local
    f16x8 vv = *(const f16x8*)&v[((long)(b * S_ + t0 + r)) * H_ + h0 + tx * 8];
#pragma unroll
    for (int c = 0; c < 8; c++) tile[tx * 8 + c][r] = vv[c];
  }
  __syncthreads();
#pragma unroll
  for (int it = 0; it < 2; it++) {
    int r = ty + it * 32;  // h-local
    f16x8 vv = *(const f16x8*)&tile[r][tx * 8];
    *(f16x8*)&vT[((long)(b * H_ + h0 + r)) * S_ + t0 + tx * 8] = vv;
  }
}

// ---------------------------------------------------------------------------
// In-place row softmax over 2048 fp16 scores + quantize to fp16.
__global__ __launch_bounds__(256) void softmax_q(f16* __restrict__ sc) {
  const long row = blockIdx.x;
  f16* p = sc + row * S_;
  const int t = threadIdx.x;
  const int wave = t >> 6, lane = t & 63;
  f16x8 v = ((const f16x8*)p)[t];
  float f[8];
  float m = -3.0e38f;
#pragma unroll
  for (int c = 0; c < 8; c++) { f[c] = (float)v[c]; m = fmaxf(m, f[c]); }
#pragma unroll
  for (int o = 32; o > 0; o >>= 1) m = fmaxf(m, __shfl_xor(m, o));
  __shared__ float redm[4], reds[4];
  if (lane == 0) redm[wave] = m;
  __syncthreads();
  m = fmaxf(fmaxf(redm[0], redm[1]), fmaxf(redm[2], redm[3]));
  float s = 0.f, e[8];
#pragma unroll
  for (int c = 0; c < 8; c++) { e[c] = expf(f[c] - m); s += e[c]; }
#pragma unroll
  for (int o = 32; o > 0; o >>= 1) s += __shfl_xor(s, o);
  if (lane == 0) reds[wave] = s;
  __syncthreads();
  s = reds[0] + reds[1] + reds[2] + reds[3];
  float inv = 1.0f / s;
  f16x8 ov;
#pragma unroll
  for (int c = 0; c < 8; c++) ov[c] = (f16)(e[c] * inv);
  ((f16x8*)p)[t] = ov;
}

// ---------------------------------------------------------------------------
extern "C" void kernel_launch(void* const* d_in, const int* in_sizes, int n_in,
                              void* d_out, int out_size, void* d_ws, size_t ws_size,
                              hipStream_t stream) {
  (void)in_sizes; (void)n_in; (void)out_size; (void)ws_size;
  const float* x  = (const float*)d_in[0];
  const float* Wq = (const float*)d_in[1];
  const float* bq = (const float*)d_in[2];
  const float* Wk = (const float*)d_in[3];
  const float* bk = (const float*)d_in[4];
  const float* Wv = (const float*)d_in[5];
  const float* bv = (const float*)d_in[6];

  char* ws = (char*)d_ws;
  f16* xh  = (f16*)ws; ws += (size_t)M_ * H_ * 2;          // 16 MiB
  f16* xl  = (f16*)ws; ws += (size_t)M_ * H_ * 2;          // 16 MiB
  f16* Wh  = (f16*)ws; ws += (size_t)3 * H_ * H_ * 2;      // 6 MiB
  f16* Wl  = (f16*)ws; ws += (size_t)3 * H_ * H_ * 2;      // 6 MiB
  f16* qkv = (f16*)ws; ws += (size_t)3 * M_ * H_ * 2;      // 48 MiB
  f16* vT  = (f16*)ws; ws += (size_t)B_ * H_ * S_ * 2;     // 16 MiB
  f16* sc  = (f16*)ws; ws += (size_t)B_ * S_ * S_ * 2;     // 32 MiB (scores, then attn in-place)

  // 1) fp32 -> fp16 hi/lo splits
  split_fp32<<<(M_ * H_ / 4 + 255) / 256, 256, 0, stream>>>(x, xh, xl, M_ * H_ / 4);
  split_fp32<<<(H_ * H_ / 4 + 255) / 256, 256, 0, stream>>>(Wq, Wh, Wl, H_ * H_ / 4);
  split_fp32<<<(H_ * H_ / 4 + 255) / 256, 256, 0, stream>>>(Wk, Wh + H_ * H_, Wl + H_ * H_, H_ * H_ / 4);
  split_fp32<<<(H_ * H_ / 4 + 255) / 256, 256, 0, stream>>>(Wv, Wh + 2 * H_ * H_, Wl + 2 * H_ * H_, H_ * H_ / 4);

  // 2) fused QKV projection + bias + quantize
  qkv_gemm<<<dim3(64, 24), 256, 0, stream>>>(xh, xl, Wh, Wl, bq, bk, bv, qkv);

  // 3) v -> vT
  transpose_v<<<dim3(32, 16, 4), 256, 0, stream>>>(qkv + (size_t)2 * M_ * H_, vT);

  // 4) scores = quantize(q @ k^T / 32), per batch
  gemm_nt<1><<<dim3(16, 16, 4), 256, 0, stream>>>(
      qkv, qkv + (size_t)M_ * H_, sc, H_, H_, S_, H_,
      (long)S_ * H_, (long)S_ * H_, (long)S_ * S_, 0.03125f);

  // 5) attn = quantize(softmax(scores)) in-place
  softmax_q<<<M_, 256, 0, stream>>>(sc);

  // 6) out = attn @ vT^T  (fp32 epilogue straight to d_out)
  gemm_nt<0><<<dim3(16, 8, 4), 256, 0, stream>>>(
      sc, vT, d_out, S_, S_, H_, S_,
      (long)S_ * S_, (long)H_ * S_, (long)S_ * H_, 1.0f);
}

// Round 2
// 319.332 us; speedup vs baseline: 1.1593x; 1.1593x over previous
//
#include <hip/hip_runtime.h>
#include <hip/hip_fp16.h>

#define B_ 4
#define S_ 2048
#define H_ 1024
#define M_ (B_ * S_)  // 8192 flattened rows of x / q / k / v

typedef _Float16 f16;
typedef _Float16 f16x8 __attribute__((ext_vector_type(8)));
typedef _Float16 f16x4 __attribute__((ext_vector_type(4)));
typedef float f32x4 __attribute__((ext_vector_type(4)));

typedef __attribute__((address_space(3))) unsigned int* lds_u32p;
typedef const __attribute__((address_space(1))) unsigned int* gbl_u32p;

// async global->LDS, 16B per lane; LDS dest is wave-uniform base + lane*16
__device__ __forceinline__ void stage16(const f16* g, f16* l) {
  __builtin_amdgcn_global_load_lds((gbl_u32p)g, (lds_u32p)l, 16, 0, 0);
}

// ---------------------------------------------------------------------------
// x (fp32) -> fp16 (RNE). 2-term QKV scheme needs only the hi plane of x.
__global__ __launch_bounds__(256) void downconvert_x(const float* __restrict__ x,
                                                     f16* __restrict__ hi, int n4) {
  int i = blockIdx.x * 256 + threadIdx.x;
  if (i >= n4) return;
  f32x4 v = ((const f32x4*)x)[i];
  f16x4 h;
#pragma unroll
  for (int c = 0; c < 4; c++) h[c] = (f16)v[c];
  ((f16x4*)hi)[i] = h;
}

// ---------------------------------------------------------------------------
// All three W matrices -> hi (fp16) + lo (fp16 residual) planes in one launch.
// blockIdx.y selects the matrix. hi+lo reproduces W to ~2^-22 relative.
__global__ __launch_bounds__(256) void split_w(const float* __restrict__ W0,
                                               const float* __restrict__ W1,
                                               const float* __restrict__ W2,
                                               f16* __restrict__ hi,
                                               f16* __restrict__ lo) {
  const int sel = blockIdx.y;
  const float* W = sel == 0 ? W0 : (sel == 1 ? W1 : W2);
  int i = blockIdx.x * 256 + threadIdx.x;  // gridDim.x * 256 == H_*H_/4 exactly
  f32x4 v = ((const f32x4*)W)[i];
  f16x4 h, l;
#pragma unroll
  for (int c = 0; c < 4; c++) {
    f16 hv = (f16)v[c];
    h[c] = hv;
    l[c] = (f16)(v[c] - (float)hv);
  }
  ((f16x4*)(hi + (long)sel * H_ * H_))[i] = h;
  ((f16x4*)(lo + (long)sel * H_ * H_))[i] = l;
}

// ---------------------------------------------------------------------------
// Fused QKV projection: qkv[sel][m][n] = fp16round( x[m][:] . W_sel[n][:] + b_sel[n] )
// 2-term scheme: xh @ (Wh + Wl).  Dropped xl@W term has RMS ~2.1e-4 (< fp16
// half-ulp of q/k/v) -- only rounding-boundary entries flip by 1 ulp.
// NT GEMM, 128x128 tile, BK=32, global_load_lds staging.
__global__ __launch_bounds__(256, 2)
void qkv_gemm(const f16* __restrict__ xh,
              const f16* __restrict__ Wh, const f16* __restrict__ Wl,
              const float* __restrict__ bq, const float* __restrict__ bk,
              const float* __restrict__ bv, f16* __restrict__ qkv) {
  __shared__ __align__(16) f16 As[128 * 32];
  __shared__ __align__(16) f16 Bs[2 * 128 * 32];  // [hi | lo]
  const int t = threadIdx.x;
  const int wave = t >> 6, lane = t & 63;
  const int quad = lane >> 4, l16 = lane & 15;
  const int wm = (wave & 1) * 64, wn = (wave >> 1) * 64;
  const int sel = blockIdx.y >> 3;             // 0=q 1=k 2=v
  const int ntile = (blockIdx.y & 7) * 128;
  const int mtile = blockIdx.x * 128;

  const f16* Ab = xh + (long)mtile * H_;
  const f16* Bbh = Wh + (long)sel * H_ * H_ + (long)ntile * H_;
  const f16* Bbl = Wl + (long)sel * H_ * H_ + (long)ntile * H_;

  const int r0 = t >> 2;        // staging row 0..63
  const int c8 = (t & 3) * 8;   // staging col (halfs)

  f32x4 acc[4][4] = {};

  for (int k0 = 0; k0 < H_; k0 += 32) {
    __syncthreads();
    stage16(Ab + (long)r0 * H_ + k0 + c8,         As + t * 8);
    stage16(Ab + (long)(r0 + 64) * H_ + k0 + c8,  As + 2048 + t * 8);
    stage16(Bbh + (long)r0 * H_ + k0 + c8,        Bs + t * 8);
    stage16(Bbh + (long)(r0 + 64) * H_ + k0 + c8, Bs + 2048 + t * 8);
    stage16(Bbl + (long)r0 * H_ + k0 + c8,        Bs + 4096 + t * 8);
    stage16(Bbl + (long)(r0 + 64) * H_ + k0 + c8, Bs + 6144 + t * 8);
    __syncthreads();
    f16x8 ah[4], bh[4], bl[4];
#pragma unroll
    for (int i = 0; i < 4; i++) {
      ah[i] = *(const f16x8*)&As[(wm + i * 16 + l16) * 32 + quad * 8];
      bh[i] = *(const f16x8*)&Bs[(wn + i * 16 + l16) * 32 + quad * 8];
      bl[i] = *(const f16x8*)&Bs[4096 + (wn + i * 16 + l16) * 32 + quad * 8];
    }
#pragma unroll
    for (int i = 0; i < 4; i++)
#pragma unroll
      for (int j = 0; j < 4; j++) {
        // small term first for accumulation accuracy
        acc[i][j] = __builtin_amdgcn_mfma_f32_16x16x32_f16(ah[i], bl[j], acc[i][j], 0, 0, 0);
        acc[i][j] = __builtin_amdgcn_mfma_f32_16x16x32_f16(ah[i], bh[j], acc[i][j], 0, 0, 0);
      }
  }

  const float* bias = sel == 0 ? bq : (sel == 1 ? bk : bv);
  f16* out = qkv + (long)sel * M_ * H_;
#pragma unroll
  for (int j = 0; j < 4; j++) {
    int n = ntile + wn + j * 16 + l16;
    float bb = bias[n];
#pragma unroll
    for (int i = 0; i < 4; i++) {
      int m = mtile + wm + i * 16 + quad * 4;
#pragma unroll
      for (int r = 0; r < 4; r++)
        out[(long)(m + r) * H_ + n] = (f16)(acc[i][j][r] + bb);
    }
  }
}

// ---------------------------------------------------------------------------
// Generic batched NT fp16 GEMM: C[z][m][n] = alpha * sum_k A[z][m][k]*B[z][n][k]
// OUT_F16=1: store quantized fp16; OUT_F16=0: store fp32.
template <int OUT_F16>
__global__ __launch_bounds__(256, 2)
void gemm_nt(const f16* __restrict__ A, const f16* __restrict__ Bm,
             void* __restrict__ C, int lda, int ldb, int ldc, int K,
             long sA, long sB, long sC, float alpha) {
  __shared__ __align__(16) f16 As[128 * 32];
  __shared__ __align__(16) f16 Bs[128 * 32];
  const int t = threadIdx.x;
  const int wave = t >> 6, lane = t & 63;
  const int quad = lane >> 4, l16 = lane & 15;
  const int wm = (wave & 1) * 64, wn = (wave >> 1) * 64;
  const f16* Ab = A + blockIdx.z * sA + (long)blockIdx.x * 128 * lda;
  const f16* Bb = Bm + blockIdx.z * sB + (long)blockIdx.y * 128 * ldb;
  const int r0 = t >> 2, c8 = (t & 3) * 8;
  f32x4 acc[4][4] = {};
  for (int k0 = 0; k0 < K; k0 += 32) {
    __syncthreads();
    stage16(Ab + (long)r0 * lda + k0 + c8,        As + t * 8);
    stage16(Ab + (long)(r0 + 64) * lda + k0 + c8, As + 2048 + t * 8);
    stage16(Bb + (long)r0 * ldb + k0 + c8,        Bs + t * 8);
    stage16(Bb + (long)(r0 + 64) * ldb + k0 + c8, Bs + 2048 + t * 8);
    __syncthreads();
    f16x8 af[4], bf[4];
#pragma unroll
    for (int i = 0; i < 4; i++) {
      af[i] = *(const f16x8*)&As[(wm + i * 16 + l16) * 32 + quad * 8];
      bf[i] = *(const f16x8*)&Bs[(wn + i * 16 + l16) * 32 + quad * 8];
    }
#pragma unroll
    for (int i = 0; i < 4; i++)
#pragma unroll
      for (int j = 0; j < 4; j++)
        acc[i][j] = __builtin_amdgcn_mfma_f32_16x16x32_f16(af[i], bf[j], acc[i][j], 0, 0, 0);
  }
  const long mb = (long)blockIdx.x * 128 + wm;
  const long nb = (long)blockIdx.y * 128 + wn;
#pragma unroll
  for (int i = 0; i < 4; i++)
#pragma unroll
    for (int j = 0; j < 4; j++) {
      long m = mb + i * 16 + quad * 4;
      long n = nb + j * 16 + l16;
#pragma unroll
      for (int r = 0; r < 4; r++) {
        float v = acc[i][j][r] * alpha;
        if (OUT_F16)
          ((f16*)C)[blockIdx.z * sC + (m + r) * ldc + n] = (f16)v;
        else
          ((float*)C)[blockIdx.z * sC + (m + r) * ldc + n] = v;
      }
    }
}

// ---------------------------------------------------------------------------
// v [b][t][h] -> vT [b][h][t]  (64x64 LDS tiles, fp16)
__global__ __launch_bounds__(256) void transpose_v(const f16* __restrict__ v,
                                                   f16* __restrict__ vT) {
  __shared__ __align__(16) f16 tile[64][72];
  const int b = blockIdx.z;
  const int t0 = blockIdx.x * 64;
  const int h0 = blockIdx.y * 64;
  const int t = threadIdx.x;
  const int tx = t & 7, ty = t >> 3;
#pragma unroll
  for (int it = 0; it < 2; it++) {
    int r = ty + it * 32;  // t-local
    f16x8 vv = *(const f16x8*)&v[((long)(b * S_ + t0 + r)) * H_ + h0 + tx * 8];
#pragma unroll
    for (int c = 0; c < 8; c++) tile[tx * 8 + c][r] = vv[c];
  }
  __syncthreads();
#pragma unroll
  for (int it = 0; it < 2; it++) {
    int r = ty + it * 32;  // h-local
    f16x8 vv = *(const f16x8*)&tile[r][tx * 8];
    *(f16x8*)&vT[((long)(b * H_ + h0 + r)) * S_ + t0 + tx * 8] = vv;
  }
}

// ---------------------------------------------------------------------------
// In-place row softmax over 2048 fp16 scores + quantize to fp16.
__global__ __launch_bounds__(256) void softmax_q(f16* __restrict__ sc) {
  const long row = blockIdx.x;
  f16* p = sc + row * S_;
  const int t = threadIdx.x;
  const int wave = t >> 6, lane = t & 63;
  f16x8 v = ((const f16x8*)p)[t];
  float f[8];
  float m = -3.0e38f;
#pragma unroll
  for (int c = 0; c < 8; c++) { f[c] = (float)v[c]; m = fmaxf(m, f[c]); }
#pragma unroll
  for (int o = 32; o > 0; o >>= 1) m = fmaxf(m, __shfl_xor(m, o));
  __shared__ float redm[4], reds[4];
  if (lane == 0) redm[wave] = m;
  __syncthreads();
  m = fmaxf(fmaxf(redm[0], redm[1]), fmaxf(redm[2], redm[3]));
  float s = 0.f, e[8];
#pragma unroll
  for (int c = 0; c < 8; c++) { e[c] = __expf(f[c] - m); s += e[c]; }
#pragma unroll
  for (int o = 32; o > 0; o >>= 1) s += __shfl_xor(s, o);
  if (lane == 0) reds[wave] = s;
  __syncthreads();
  s = reds[0] + reds[1] + reds[2] + reds[3];
  float inv = 1.0f / s;
  f16x8 ov;
#pragma unroll
  for (int c = 0; c < 8; c++) ov[c] = (f16)(e[c] * inv);
  ((f16x8*)p)[t] = ov;
}

// ---------------------------------------------------------------------------
extern "C" void kernel_launch(void* const* d_in, const int* in_sizes, int n_in,
                              void* d_out, int out_size, void* d_ws, size_t ws_size,
                              hipStream_t stream) {
  (void)in_sizes; (void)n_in; (void)out_size; (void)ws_size;
  const float* x  = (const float*)d_in[0];
  const float* Wq = (const float*)d_in[1];
  const float* bq = (const float*)d_in[2];
  const float* Wk = (const float*)d_in[3];
  const float* bk = (const float*)d_in[4];
  const float* Wv = (const float*)d_in[5];
  const float* bv = (const float*)d_in[6];

  char* ws = (char*)d_ws;
  f16* xh  = (f16*)ws; ws += (size_t)M_ * H_ * 2;          // 16 MiB
  f16* Wh  = (f16*)ws; ws += (size_t)3 * H_ * H_ * 2;      // 6 MiB
  f16* Wl  = (f16*)ws; ws += (size_t)3 * H_ * H_ * 2;      // 6 MiB
  f16* qkv = (f16*)ws; ws += (size_t)3 * M_ * H_ * 2;      // 48 MiB
  f16* vT  = (f16*)ws; ws += (size_t)B_ * H_ * S_ * 2;     // 16 MiB
  f16* sc  = (f16*)ws; ws += (size_t)B_ * S_ * S_ * 2;     // 32 MiB (scores, then attn in-place)

  // 1) x -> fp16; W -> fp16 hi/lo split (all three in one launch)
  downconvert_x<<<M_ * H_ / 4 / 256, 256, 0, stream>>>(x, xh, M_ * H_ / 4);
  split_w<<<dim3(H_ * H_ / 4 / 256, 3), 256, 0, stream>>>(Wq, Wk, Wv, Wh, Wl);

  // 2) fused QKV projection + bias + quantize (2-term: xh @ (Wh+Wl))
  qkv_gemm<<<dim3(64, 24), 256, 0, stream>>>(xh, Wh, Wl, bq, bk, bv, qkv);

  // 3) v -> vT
  transpose_v<<<dim3(32, 16, 4), 256, 0, stream>>>(qkv + (size_t)2 * M_ * H_, vT);

  // 4) scores = quantize(q @ k^T / 32), per batch
  gemm_nt<1><<<dim3(16, 16, 4), 256, 0, stream>>>(
      qkv, qkv + (size_t)M_ * H_, sc, H_, H_, S_, H_,
      (long)S_ * H_, (long)S_ * H_, (long)S_ * S_, 0.03125f);

  // 5) attn = quantize(softmax(scores)) in-place
  softmax_q<<<M_, 256, 0, stream>>>(sc);

  // 6) out = attn @ vT^T  (fp32 epilogue straight to d_out)
  gemm_nt<0><<<dim3(16, 8, 4), 256, 0, stream>>>(
      sc, vT, d_out, S_, S_, H_, S_,
      (long)S_ * S_, (long)H_ * S_, (long)S_ * H_, 1.0f);
}

// Round 3
// 284.921 us; speedup vs baseline: 1.2993x; 1.1208x over previous
//
#include <hip/hip_runtime.h>
#include <hip/hip_fp16.h>

#define B_ 4
#define S_ 2048
#define H_ 1024
#define M_ (B_ * S_)  // 8192 flattened rows of x / q / k / v

typedef _Float16 f16;
typedef _Float16 f16x8 __attribute__((ext_vector_type(8)));
typedef _Float16 f16x4 __attribute__((ext_vector_type(4)));
typedef float f32x4 __attribute__((ext_vector_type(4)));

typedef __attribute__((address_space(3))) unsigned int* lds_u32p;
typedef const __attribute__((address_space(1))) unsigned int* gbl_u32p;

// async global->LDS, 16B per lane; LDS dest is wave-uniform base + lane*16
__device__ __forceinline__ void stage16(const f16* g, f16* l) {
  __builtin_amdgcn_global_load_lds((gbl_u32p)g, (lds_u32p)l, 16, 0, 0);
}

// ---------------------------------------------------------------------------
// x (fp32) -> fp16 (RNE).
__global__ __launch_bounds__(256) void downconvert_x(const float* __restrict__ x,
                                                     f16* __restrict__ hi, int n4) {
  int i = blockIdx.x * 256 + threadIdx.x;
  if (i >= n4) return;
  f32x4 v = ((const f32x4*)x)[i];
  f16x4 h;
#pragma unroll
  for (int c = 0; c < 4; c++) h[c] = (f16)v[c];
  ((f16x4*)hi)[i] = h;
}

// All three W matrices -> fp16 in one launch (blockIdx.y selects matrix).
__global__ __launch_bounds__(256) void downconvert_w(const float* __restrict__ W0,
                                                     const float* __restrict__ W1,
                                                     const float* __restrict__ W2,
                                                     f16* __restrict__ hi) {
  const int sel = blockIdx.y;
  const float* W = sel == 0 ? W0 : (sel == 1 ? W1 : W2);
  int i = blockIdx.x * 256 + threadIdx.x;  // gridDim.x * 256 == H_*H_/4 exactly
  f32x4 v = ((const f32x4*)W)[i];
  f16x4 h;
#pragma unroll
  for (int c = 0; c < 4; c++) h[c] = (f16)v[c];
  ((f16x4*)(hi + (long)sel * H_ * H_))[i] = h;
}

// ---------------------------------------------------------------------------
// Fused QKV projection: qkv[sel][m][n] = fp16round( x[m][:] . W_sel[n][:] + b_sel[n] )
// Pure fp16: xh @ Wh. Error budget (vs fp32 ref, pre-quantize): x-rounding term
// 2.8e-4 + W-rounding term 2.8e-4 (rss 4e-4) -- under the q/k/v fp16 half-ulp
// except rounding-boundary entries (1-ulp flips that wash out downstream).
// NT GEMM, 128x128 tile, BK=32, global_load_lds staging.
__global__ __launch_bounds__(256, 2)
void qkv_gemm(const f16* __restrict__ xh, const f16* __restrict__ Wh,
              const float* __restrict__ bq, const float* __restrict__ bk,
              const float* __restrict__ bv, f16* __restrict__ qkv) {
  __shared__ __align__(16) f16 As[128 * 32];
  __shared__ __align__(16) f16 Bs[128 * 32];
  const int t = threadIdx.x;
  const int wave = t >> 6, lane = t & 63;
  const int quad = lane >> 4, l16 = lane & 15;
  const int wm = (wave & 1) * 64, wn = (wave >> 1) * 64;
  const int sel = blockIdx.y >> 3;             // 0=q 1=k 2=v
  const int ntile = (blockIdx.y & 7) * 128;
  const int mtile = blockIdx.x * 128;

  const f16* Ab = xh + (long)mtile * H_;
  const f16* Bb = Wh + (long)sel * H_ * H_ + (long)ntile * H_;

  const int r0 = t >> 2;        // staging row 0..63
  const int c8 = (t & 3) * 8;   // staging col (halfs)

  f32x4 acc[4][4] = {};

  for (int k0 = 0; k0 < H_; k0 += 32) {
    __syncthreads();
    stage16(Ab + (long)r0 * H_ + k0 + c8,        As + t * 8);
    stage16(Ab + (long)(r0 + 64) * H_ + k0 + c8, As + 2048 + t * 8);
    stage16(Bb + (long)r0 * H_ + k0 + c8,        Bs + t * 8);
    stage16(Bb + (long)(r0 + 64) * H_ + k0 + c8, Bs + 2048 + t * 8);
    __syncthreads();
    f16x8 ah[4], bh[4];
#pragma unroll
    for (int i = 0; i < 4; i++) {
      ah[i] = *(const f16x8*)&As[(wm + i * 16 + l16) * 32 + quad * 8];
      bh[i] = *(const f16x8*)&Bs[(wn + i * 16 + l16) * 32 + quad * 8];
    }
#pragma unroll
    for (int i = 0; i < 4; i++)
#pragma unroll
      for (int j = 0; j < 4; j++)
        acc[i][j] = __builtin_amdgcn_mfma_f32_16x16x32_f16(ah[i], bh[j], acc[i][j], 0, 0, 0);
  }

  const float* bias = sel == 0 ? bq : (sel == 1 ? bk : bv);
  f16* out = qkv + (long)sel * M_ * H_;
#pragma unroll
  for (int j = 0; j < 4; j++) {
    int n = ntile + wn + j * 16 + l16;
    float bb = bias[n];
#pragma unroll
    for (int i = 0; i < 4; i++) {
      int m = mtile + wm + i * 16 + quad * 4;
#pragma unroll
      for (int r = 0; r < 4; r++)
        out[(long)(m + r) * H_ + n] = (f16)(acc[i][j][r] + bb);
    }
  }
}

// ---------------------------------------------------------------------------
// Generic batched NT fp16 GEMM: C[z][m][n] = alpha * sum_k A[z][m][k]*B[z][n][k]
// OUT_F16=1: store quantized fp16; OUT_F16=0: store fp32.
template <int OUT_F16>
__global__ __launch_bounds__(256, 2)
void gemm_nt(const f16* __restrict__ A, const f16* __restrict__ Bm,
             void* __restrict__ C, int lda, int ldb, int ldc, int K,
             long sA, long sB, long sC, float alpha) {
  __shared__ __align__(16) f16 As[128 * 32];
  __shared__ __align__(16) f16 Bs[128 * 32];
  const int t = threadIdx.x;
  const int wave = t >> 6, lane = t & 63;
  const int quad = lane >> 4, l16 = lane & 15;
  const int wm = (wave & 1) * 64, wn = (wave >> 1) * 64;
  const f16* Ab = A + blockIdx.z * sA + (long)blockIdx.x * 128 * lda;
  const f16* Bb = Bm + blockIdx.z * sB + (long)blockIdx.y * 128 * ldb;
  const int r0 = t >> 2, c8 = (t & 3) * 8;
  f32x4 acc[4][4] = {};
  for (int k0 = 0; k0 < K; k0 += 32) {
    __syncthreads();
    stage16(Ab + (long)r0 * lda + k0 + c8,        As + t * 8);
    stage16(Ab + (long)(r0 + 64) * lda + k0 + c8, As + 2048 + t * 8);
    stage16(Bb + (long)r0 * ldb + k0 + c8,        Bs + t * 8);
    stage16(Bb + (long)(r0 + 64) * ldb + k0 + c8, Bs + 2048 + t * 8);
    __syncthreads();
    f16x8 af[4], bf[4];
#pragma unroll
    for (int i = 0; i < 4; i++) {
      af[i] = *(const f16x8*)&As[(wm + i * 16 + l16) * 32 + quad * 8];
      bf[i] = *(const f16x8*)&Bs[(wn + i * 16 + l16) * 32 + quad * 8];
    }
#pragma unroll
    for (int i = 0; i < 4; i++)
#pragma unroll
      for (int j = 0; j < 4; j++)
        acc[i][j] = __builtin_amdgcn_mfma_f32_16x16x32_f16(af[i], bf[j], acc[i][j], 0, 0, 0);
  }
  const long mb = (long)blockIdx.x * 128 + wm;
  const long nb = (long)blockIdx.y * 128 + wn;
#pragma unroll
  for (int i = 0; i < 4; i++)
#pragma unroll
    for (int j = 0; j < 4; j++) {
      long m = mb + i * 16 + quad * 4;
      long n = nb + j * 16 + l16;
#pragma unroll
      for (int r = 0; r < 4; r++) {
        float v = acc[i][j][r] * alpha;
        if (OUT_F16)
          ((f16*)C)[blockIdx.z * sC + (m + r) * ldc + n] = (f16)v;
        else
          ((float*)C)[blockIdx.z * sC + (m + r) * ldc + n] = v;
      }
    }
}

// ---------------------------------------------------------------------------
// v [b][t][h] -> vT [b][h][t]  (64x64 LDS tiles, fp16)
__global__ __launch_bounds__(256) void transpose_v(const f16* __restrict__ v,
                                                   f16* __restrict__ vT) {
  __shared__ __align__(16) f16 tile[64][72];
  const int b = blockIdx.z;
  const int t0 = blockIdx.x * 64;
  const int h0 = blockIdx.y * 64;
  const int t = threadIdx.x;
  const int tx = t & 7, ty = t >> 3;
#pragma unroll
  for (int it = 0; it < 2; it++) {
    int r = ty + it * 32;  // t-local
    f16x8 vv = *(const f16x8*)&v[((long)(b * S_ + t0 + r)) * H_ + h0 + tx * 8];
#pragma unroll
    for (int c = 0; c < 8; c++) tile[tx * 8 + c][r] = vv[c];
  }
  __syncthreads();
#pragma unroll
  for (int it = 0; it < 2; it++) {
    int r = ty + it * 32;  // h-local
    f16x8 vv = *(const f16x8*)&tile[r][tx * 8];
    *(f16x8*)&vT[((long)(b * H_ + h0 + r)) * S_ + t0 + tx * 8] = vv;
  }
}

// ---------------------------------------------------------------------------
// In-place row softmax over 2048 fp16 scores + quantize to fp16.
__global__ __launch_bounds__(256) void softmax_q(f16* __restrict__ sc) {
  const long row = blockIdx.x;
  f16* p = sc + row * S_;
  const int t = threadIdx.x;
  const int wave = t >> 6, lane = t & 63;
  f16x8 v = ((const f16x8*)p)[t];
  float f[8];
  float m = -3.0e38f;
#pragma unroll
  for (int c = 0; c < 8; c++) { f[c] = (float)v[c]; m = fmaxf(m, f[c]); }
#pragma unroll
  for (int o = 32; o > 0; o >>= 1) m = fmaxf(m, __shfl_xor(m, o));
  __shared__ float redm[4], reds[4];
  if (lane == 0) redm[wave] = m;
  __syncthreads();
  m = fmaxf(fmaxf(redm[0], redm[1]), fmaxf(redm[2], redm[3]));
  float s = 0.f, e[8];
#pragma unroll
  for (int c = 0; c < 8; c++) { e[c] = __expf(f[c] - m); s += e[c]; }
#pragma unroll
  for (int o = 32; o > 0; o >>= 1) s += __shfl_xor(s, o);
  if (lane == 0) reds[wave] = s;
  __syncthreads();
  s = reds[0] + reds[1] + reds[2] + reds[3];
  float inv = 1.0f / s;
  f16x8 ov;
#pragma unroll
  for (int c = 0; c < 8; c++) ov[c] = (f16)(e[c] * inv);
  ((f16x8*)p)[t] = ov;
}

// ---------------------------------------------------------------------------
extern "C" void kernel_launch(void* const* d_in, const int* in_sizes, int n_in,
                              void* d_out, int out_size, void* d_ws, size_t ws_size,
                              hipStream_t stream) {
  (void)in_sizes; (void)n_in; (void)out_size; (void)ws_size;
  const float* x  = (const float*)d_in[0];
  const float* Wq = (const float*)d_in[1];
  const float* bq = (const float*)d_in[2];
  const float* Wk = (const float*)d_in[3];
  const float* bk = (const float*)d_in[4];
  const float* Wv = (const float*)d_in[5];
  const float* bv = (const float*)d_in[6];

  char* ws = (char*)d_ws;
  f16* xh  = (f16*)ws; ws += (size_t)M_ * H_ * 2;          // 16 MiB
  f16* Wh  = (f16*)ws; ws += (size_t)3 * H_ * H_ * 2;      // 6 MiB
  f16* qkv = (f16*)ws; ws += (size_t)3 * M_ * H_ * 2;      // 48 MiB
  f16* vT  = (f16*)ws; ws += (size_t)B_ * H_ * S_ * 2;     // 16 MiB
  f16* sc  = (f16*)ws; ws += (size_t)B_ * S_ * S_ * 2;     // 32 MiB (scores, then attn in-place)

  // 1) x, W -> fp16
  downconvert_x<<<M_ * H_ / 4 / 256, 256, 0, stream>>>(x, xh, M_ * H_ / 4);
  downconvert_w<<<dim3(H_ * H_ / 4 / 256, 3), 256, 0, stream>>>(Wq, Wk, Wv, Wh);

  // 2) fused QKV projection + bias + quantize (pure fp16)
  qkv_gemm<<<dim3(64, 24), 256, 0, stream>>>(xh, Wh, bq, bk, bv, qkv);

  // 3) v -> vT
  transpose_v<<<dim3(32, 16, 4), 256, 0, stream>>>(qkv + (size_t)2 * M_ * H_, vT);

  // 4) scores = quantize(q @ k^T / 32), per batch
  gemm_nt<1><<<dim3(16, 16, 4), 256, 0, stream>>>(
      qkv, qkv + (size_t)M_ * H_, sc, H_, H_, S_, H_,
      (long)S_ * H_, (long)S_ * H_, (long)S_ * S_, 0.03125f);

  // 5) attn = quantize(softmax(scores)) in-place
  softmax_q<<<M_, 256, 0, stream>>>(sc);

  // 6) out = attn @ vT^T  (fp32 epilogue straight to d_out)
  gemm_nt<0><<<dim3(16, 8, 4), 256, 0, stream>>>(
      sc, vT, d_out, S_, S_, H_, S_,
      (long)S_ * S_, (long)H_ * S_, (long)S_ * H_, 1.0f);
}

// Round 4
// 252.025 us; speedup vs baseline: 1.4690x; 1.1305x over previous
//
#include <hip/hip_runtime.h>
#include <hip/hip_fp16.h>

#define B_ 4
#define S_ 2048
#define H_ 1024
#define M_ (B_ * S_)  // 8192 flattened rows of x / q / k / v

typedef _Float16 f16;
typedef _Float16 f16x8 __attribute__((ext_vector_type(8)));
typedef _Float16 f16x4 __attribute__((ext_vector_type(4)));
typedef float f32x4 __attribute__((ext_vector_type(4)));

typedef __attribute__((address_space(3))) unsigned int* lds_u32p;
typedef const __attribute__((address_space(1))) unsigned int* gbl_u32p;

// async global->LDS, 16B per lane; LDS dest is wave-uniform base + lane*16
__device__ __forceinline__ void stage16(const f16* g, f16* l) {
  __builtin_amdgcn_global_load_lds((gbl_u32p)g, (lds_u32p)l, 16, 0, 0);
}

// ---------------------------------------------------------------------------
// One launch: x (8192 blocks) then Wq/Wk/Wv (1024 blocks each) -> fp16 RNE.
__global__ __launch_bounds__(256) void downconvert_all(
    const float* __restrict__ x, const float* __restrict__ W0,
    const float* __restrict__ W1, const float* __restrict__ W2,
    f16* __restrict__ xh, f16* __restrict__ Wh) {
  const int b = blockIdx.x;
  const float* src;
  f16* dst;
  long i;
  if (b < M_ * H_ / 1024) {  // 8192 x-blocks
    src = x; dst = xh;
    i = (long)b * 256 + threadIdx.x;
  } else {
    const int wb = b - M_ * H_ / 1024;
    const int sel = wb >> 10;               // 1024 blocks per W
    src = sel == 0 ? W0 : (sel == 1 ? W1 : W2);
    dst = Wh + (long)sel * H_ * H_;
    i = (long)(wb & 1023) * 256 + threadIdx.x;
  }
  f32x4 v = ((const f32x4*)src)[i];
  f16x4 h;
#pragma unroll
  for (int c = 0; c < 4; c++) h[c] = (f16)v[c];
  ((f16x4*)dst)[i] = h;
}

// ---------------------------------------------------------------------------
// Fused QKV projection: qkv[sel][m][n] = fp16round( x[m][:] . W_sel[n][:] + b_sel[n] )
// Pure fp16 xh @ Wh (error budget: rss 4e-4 pre-quantize, under fp16 half-ulp).
// NT GEMM, 128x128 tile, BK=64 as two BK=32 sub-chunks per barrier (32 MFMA
// per barrier; LDS layout stays two row-major 128x32 tiles so global_load_lds
// lane ordering and bank behavior match BK=32).
// sel==2 (V) is written TRANSPOSED to vT[b][h][t] (f16x4 stores along t).
__global__ __launch_bounds__(256, 2)
void qkv_gemm(const f16* __restrict__ xh, const f16* __restrict__ Wh,
              const float* __restrict__ bq, const float* __restrict__ bk,
              const float* __restrict__ bv, f16* __restrict__ qkv,
              f16* __restrict__ vT) {
  __shared__ __align__(16) f16 As[2 * 128 * 32];  // [chunk0 | chunk1]
  __shared__ __align__(16) f16 Bs[2 * 128 * 32];
  const int t = threadIdx.x;
  const int wave = t >> 6, lane = t & 63;
  const int quad = lane >> 4, l16 = lane & 15;
  const int wm = (wave & 1) * 64, wn = (wave >> 1) * 64;
  const int sel = blockIdx.y >> 3;             // 0=q 1=k 2=v
  const int ntile = (blockIdx.y & 7) * 128;
  const int mtile = blockIdx.x * 128;

  const f16* Ab = xh + (long)mtile * H_;
  const f16* Bb = Wh + (long)sel * H_ * H_ + (long)ntile * H_;

  const int r0 = t >> 2;        // staging row 0..63
  const int c8 = (t & 3) * 8;   // staging col (halfs)

  f32x4 acc[4][4] = {};

  for (int k0 = 0; k0 < H_; k0 += 64) {
    __syncthreads();
    stage16(Ab + (long)r0 * H_ + k0 + c8,             As + t * 8);
    stage16(Ab + (long)(r0 + 64) * H_ + k0 + c8,      As + 2048 + t * 8);
    stage16(Ab + (long)r0 * H_ + k0 + 32 + c8,        As + 4096 + t * 8);
    stage16(Ab + (long)(r0 + 64) * H_ + k0 + 32 + c8, As + 6144 + t * 8);
    stage16(Bb + (long)r0 * H_ + k0 + c8,             Bs + t * 8);
    stage16(Bb + (long)(r0 + 64) * H_ + k0 + c8,      Bs + 2048 + t * 8);
    stage16(Bb + (long)r0 * H_ + k0 + 32 + c8,        Bs + 4096 + t * 8);
    stage16(Bb + (long)(r0 + 64) * H_ + k0 + 32 + c8, Bs + 6144 + t * 8);
    __syncthreads();
#pragma unroll
    for (int kk = 0; kk < 2; kk++) {
      f16x8 ah[4], bh[4];
#pragma unroll
      for (int i = 0; i < 4; i++) {
        ah[i] = *(const f16x8*)&As[kk * 4096 + (wm + i * 16 + l16) * 32 + quad * 8];
        bh[i] = *(const f16x8*)&Bs[kk * 4096 + (wn + i * 16 + l16) * 32 + quad * 8];
      }
#pragma unroll
      for (int i = 0; i < 4; i++)
#pragma unroll
        for (int j = 0; j < 4; j++)
          acc[i][j] = __builtin_amdgcn_mfma_f32_16x16x32_f16(ah[i], bh[j], acc[i][j], 0, 0, 0);
    }
  }

  const float* bias = sel == 0 ? bq : (sel == 1 ? bk : bv);
  if (sel == 2) {
    // V transposed: vT[(b*H + n)*S + t_pos], b = m>>11, t_pos = m&2047.
    // r=0..3 are consecutive m -> consecutive t_pos -> f16x4 store.
#pragma unroll
    for (int j = 0; j < 4; j++) {
      int n = ntile + wn + j * 16 + l16;
      float bb = bias[n];
#pragma unroll
      for (int i = 0; i < 4; i++) {
        int m = mtile + wm + i * 16 + quad * 4;
        f16x4 pack;
#pragma unroll
        for (int r = 0; r < 4; r++) pack[r] = (f16)(acc[i][j][r] + bb);
        *(f16x4*)&vT[((long)(m >> 11) * H_ + n) * S_ + (m & 2047)] = pack;
      }
    }
  } else {
    f16* out = qkv + (long)sel * M_ * H_;
#pragma unroll
    for (int j = 0; j < 4; j++) {
      int n = ntile + wn + j * 16 + l16;
      float bb = bias[n];
#pragma unroll
      for (int i = 0; i < 4; i++) {
        int m = mtile + wm + i * 16 + quad * 4;
#pragma unroll
        for (int r = 0; r < 4; r++)
          out[(long)(m + r) * H_ + n] = (f16)(acc[i][j][r] + bb);
      }
    }
  }
}

// ---------------------------------------------------------------------------
// Generic batched NT fp16 GEMM: C[z][m][n] = alpha * sum_k A[z][m][k]*B[z][n][k]
// BK=64 as two BK=32 sub-chunks per barrier.
// OUT_F16=1: store quantized fp16; OUT_F16=0: store fp32.
template <int OUT_F16>
__global__ __launch_bounds__(256, 2)
void gemm_nt(const f16* __restrict__ A, const f16* __restrict__ Bm,
             void* __restrict__ C, int lda, int ldb, int ldc, int K,
             long sA, long sB, long sC, float alpha) {
  __shared__ __align__(16) f16 As[2 * 128 * 32];
  __shared__ __align__(16) f16 Bs[2 * 128 * 32];
  const int t = threadIdx.x;
  const int wave = t >> 6, lane = t & 63;
  const int quad = lane >> 4, l16 = lane & 15;
  const int wm = (wave & 1) * 64, wn = (wave >> 1) * 64;
  const f16* Ab = A + blockIdx.z * sA + (long)blockIdx.x * 128 * lda;
  const f16* Bb = Bm + blockIdx.z * sB + (long)blockIdx.y * 128 * ldb;
  const int r0 = t >> 2, c8 = (t & 3) * 8;
  f32x4 acc[4][4] = {};
  for (int k0 = 0; k0 < K; k0 += 64) {
    __syncthreads();
    stage16(Ab + (long)r0 * lda + k0 + c8,             As + t * 8);
    stage16(Ab + (long)(r0 + 64) * lda + k0 + c8,      As + 2048 + t * 8);
    stage16(Ab + (long)r0 * lda + k0 + 32 + c8,        As + 4096 + t * 8);
    stage16(Ab + (long)(r0 + 64) * lda + k0 + 32 + c8, As + 6144 + t * 8);
    stage16(Bb + (long)r0 * ldb + k0 + c8,             Bs + t * 8);
    stage16(Bb + (long)(r0 + 64) * ldb + k0 + c8,      Bs + 2048 + t * 8);
    stage16(Bb + (long)r0 * ldb + k0 + 32 + c8,        Bs + 4096 + t * 8);
    stage16(Bb + (long)(r0 + 64) * ldb + k0 + 32 + c8, Bs + 6144 + t * 8);
    __syncthreads();
#pragma unroll
    for (int kk = 0; kk < 2; kk++) {
      f16x8 af[4], bf[4];
#pragma unroll
      for (int i = 0; i < 4; i++) {
        af[i] = *(const f16x8*)&As[kk * 4096 + (wm + i * 16 + l16) * 32 + quad * 8];
        bf[i] = *(const f16x8*)&Bs[kk * 4096 + (wn + i * 16 + l16) * 32 + quad * 8];
      }
#pragma unroll
      for (int i = 0; i < 4; i++)
#pragma unroll
        for (int j = 0; j < 4; j++)
          acc[i][j] = __builtin_amdgcn_mfma_f32_16x16x32_f16(af[i], bf[j], acc[i][j], 0, 0, 0);
    }
  }
  const long mb = (long)blockIdx.x * 128 + wm;
  const long nb = (long)blockIdx.y * 128 + wn;
#pragma unroll
  for (int i = 0; i < 4; i++)
#pragma unroll
    for (int j = 0; j < 4; j++) {
      long m = mb + i * 16 + quad * 4;
      long n = nb + j * 16 + l16;
#pragma unroll
      for (int r = 0; r < 4; r++) {
        float v = acc[i][j][r] * alpha;
        if (OUT_F16)
          ((f16*)C)[blockIdx.z * sC + (m + r) * ldc + n] = (f16)v;
        else
          ((float*)C)[blockIdx.z * sC + (m + r) * ldc + n] = v;
      }
    }
}

// ---------------------------------------------------------------------------
// In-place row softmax over 2048 fp16 scores + quantize to fp16.
__global__ __launch_bounds__(256) void softmax_q(f16* __restrict__ sc) {
  const long row = blockIdx.x;
  f16* p = sc + row * S_;
  const int t = threadIdx.x;
  const int wave = t >> 6, lane = t & 63;
  f16x8 v = ((const f16x8*)p)[t];
  float f[8];
  float m = -3.0e38f;
#pragma unroll
  for (int c = 0; c < 8; c++) { f[c] = (float)v[c]; m = fmaxf(m, f[c]); }
#pragma unroll
  for (int o = 32; o > 0; o >>= 1) m = fmaxf(m, __shfl_xor(m, o));
  __shared__ float redm[4], reds[4];
  if (lane == 0) redm[wave] = m;
  __syncthreads();
  m = fmaxf(fmaxf(redm[0], redm[1]), fmaxf(redm[2], redm[3]));
  float s = 0.f, e[8];
#pragma unroll
  for (int c = 0; c < 8; c++) { e[c] = __expf(f[c] - m); s += e[c]; }
#pragma unroll
  for (int o = 32; o > 0; o >>= 1) s += __shfl_xor(s, o);
  if (lane == 0) reds[wave] = s;
  __syncthreads();
  s = reds[0] + reds[1] + reds[2] + reds[3];
  float inv = 1.0f / s;
  f16x8 ov;
#pragma unroll
  for (int c = 0; c < 8; c++) ov[c] = (f16)(e[c] * inv);
  ((f16x8*)p)[t] = ov;
}

// ---------------------------------------------------------------------------
extern "C" void kernel_launch(void* const* d_in, const int* in_sizes, int n_in,
                              void* d_out, int out_size, void* d_ws, size_t ws_size,
                              hipStream_t stream) {
  (void)in_sizes; (void)n_in; (void)out_size; (void)ws_size;
  const float* x  = (const float*)d_in[0];
  const float* Wq = (const float*)d_in[1];
  const float* bq = (const float*)d_in[2];
  const float* Wk = (const float*)d_in[3];
  const float* bk = (const float*)d_in[4];
  const float* Wv = (const float*)d_in[5];
  const float* bv = (const float*)d_in[6];

  char* ws = (char*)d_ws;
  f16* xh  = (f16*)ws; ws += (size_t)M_ * H_ * 2;          // 16 MiB
  f16* Wh  = (f16*)ws; ws += (size_t)3 * H_ * H_ * 2;      // 6 MiB
  f16* qkv = (f16*)ws; ws += (size_t)2 * M_ * H_ * 2;      // 32 MiB (q, k)
  f16* vT  = (f16*)ws; ws += (size_t)B_ * H_ * S_ * 2;     // 16 MiB
  f16* sc  = (f16*)ws; ws += (size_t)B_ * S_ * S_ * 2;     // 32 MiB (scores, then attn in-place)

  // 1) x, Wq/Wk/Wv -> fp16 in one launch
  downconvert_all<<<M_ * H_ / 1024 + 3 * H_ * H_ / 1024, 256, 0, stream>>>(
      x, Wq, Wk, Wv, xh, Wh);

  // 2) fused QKV projection + bias + quantize; V written transposed
  qkv_gemm<<<dim3(64, 24), 256, 0, stream>>>(xh, Wh, bq, bk, bv, qkv, vT);

  // 3) scores = quantize(q @ k^T / 32), per batch
  gemm_nt<1><<<dim3(16, 16, 4), 256, 0, stream>>>(
      qkv, qkv + (size_t)M_ * H_, sc, H_, H_, S_, H_,
      (long)S_ * H_, (long)S_ * H_, (long)S_ * S_, 0.03125f);

  // 4) attn = quantize(softmax(scores)) in-place
  softmax_q<<<M_, 256, 0, stream>>>(sc);

  // 5) out = attn @ vT^T  (fp32 epilogue straight to d_out)
  gemm_nt<0><<<dim3(16, 8, 4), 256, 0, stream>>>(
      sc, vT, d_out, S_, S_, H_, S_,
      (long)S_ * S_, (long)H_ * S_, (long)S_ * H_, 1.0f);
}